// Round 13
// baseline (1976.985 us; speedup 1.0000x reference)
//
#include <hip/hip_runtime.h>

#define H 51
#define TSEQ 2048
#define BB 32            // batch per block = 2 groups x 16 (fills MFMA columns twice)
#define THREADS 1024     // 16 waves: 0-11 tiles, 12 flush, 13 L1-helper, 14 L2-helper+y, 15 pf+x

typedef _Float16 __attribute__((ext_vector_type(8))) half8;  // 8 f16 (MFMA A/B frag)
typedef float    __attribute__((ext_vector_type(4))) float4v;

#define LOG2E    1.44269504f
#define TWOLOG2E 2.88539008f

// Fused LSTM cell elementwise update: 7 transcendentals (5 exp2 + 2 rcp),
// fma-refactored.  Inputs pre-scaled: a[0]=i*log2e, a[1]=f*log2e,
// a[2]=g*2log2e, a[3]=o*log2e.
__device__ __forceinline__ float lstm_ew(float4v a, float& c) {
    float eA = __builtin_amdgcn_exp2f(-a[0]);
    float eB = __builtin_amdgcn_exp2f(a[2]);
    float eF = __builtin_amdgcn_exp2f(-a[1]);
    float pA = eA + 1.0f, pB = eB + 1.0f, pF = eF + 1.0f;
    float dAB = pA * pB;
    float t0  = fmaf(eB, pF, -pF);                 // (eB-1)*pF
    float num = fmaf(c, dAB, t0);
    float r   = __builtin_amdgcn_rcpf(dAB * pF);
    float cn  = num * r;
    c = cn;
    float uD = fminf(cn * TWOLOG2E, 126.0f);
    float eD = __builtin_amdgcn_exp2f(uD);
    float eC = __builtin_amdgcn_exp2f(-a[3]);
    float pD = eD + 1.0f;
    float r2 = __builtin_amdgcn_rcpf(fmaf(eC, pD, pD));  // (eC+1)*pD
    return fmaf(eD, r2, -r2);                      // (eD-1)*r2
}

// R13 = R12 (1208us) + TWO independent batch-groups per block (BB=32):
//  R12's null result proved the VALU-issue model exhausted — the step is set
//  by ~600 cyc of fixed per-step overhead (barrier drain + post-barrier LDS
//  latency + exposed h1 chain).  Two groups of 16 batches share one barrier
//  interval: group B's independent issue fills group A's latency bubbles and
//  the fixed overhead is amortized over 2 group-steps.  Grid 64 blocks.
//  Per-group math identical to R12 -> absmax bit-identical.
//  Carried: x-injection slot 51 (R8), split-phase reads (R7), y-fold row 204
//  (R5), recompute helpers (R4), chained mm2 (R12), fma ew (R10).
__global__ __launch_bounds__(THREADS)
void lstm_w32_kernel(const float* __restrict__ input,
                     const float* __restrict__ W_ih1, const float* __restrict__ W_hh1,
                     const float* __restrict__ b_ih1, const float* __restrict__ b_hh1,
                     const float* __restrict__ W_ih2, const float* __restrict__ W_hh2,
                     const float* __restrict__ b_ih2, const float* __restrict__ b_hh2,
                     const float* __restrict__ W_lin, const float* __restrict__ b_lin,
                     float* __restrict__ out)
{
    __shared__ half8 hb1[2][2][2][64];   // [group][parity][kstep][fraglane]
    __shared__ half8 hb2[2][2][2][64];
    __shared__ float xss[2][2][64 * 17]; // [group][chunk-parity][i*17+b]
    __shared__ float ybf[2][128][17];    // [group][t&127][batch]

    const int tid  = threadIdx.x;
    const int wv   = tid >> 6;           // 0..15
    const int lane = tid & 63;
    const int n    = lane & 15;          // MFMA col = batch-in-group
    const int qd   = lane >> 4;          // quad
    const int b0   = blockIdx.x * BB;
    const float blin = b_lin[0];

    if (tid < 512) {
        half8 z = {0,0,0,0,0,0,0,0};
        (&hb1[0][0][0][0])[tid] = z;
        (&hb2[0][0][0][0])[tid] = z;
    }

    if (wv == 15) {                      // x chunk 0, both groups (32 batches)
#pragma unroll
        for (int k = 0; k < 32; ++k)
            xss[k >> 4][0][lane * 17 + (k & 15)] =
                input[(size_t)(b0 + k) * TSEQ + lane];
    }

    // ---- persistent A-fragments (shared by both groups) ----
    half8 wa1[2];                        // W_hh1 (K=64) + W_ih1 at k=51
    half8 wa2[4];                        // s<2: W_ih2 (k=h1); s>=2: W_hh2 (k=h2); row204=W_lin
    {
        const int tw1 = (wv < 12) ? wv : ((wv == 13) ? 12 : 13);
        const int tw2 = (wv < 12) ? wv : ((wv == 14) ? 12 : 13);
        {
            const int arow = tw1 * 16 + n;
            const int cell = arow >> 2, gate = arow & 3;
            const int orow = gate * H + cell;
            const float gsc = (gate == 2) ? TWOLOG2E : LOG2E;
            const bool rok = (arow < 4 * H);
#pragma unroll
            for (int s = 0; s < 2; ++s)
#pragma unroll
                for (int j = 0; j < 8; ++j) {
                    int kk = s * 32 + qd * 8 + j;
                    float w = 0.f;
                    if (rok) {
                        if (kk < H)        w = gsc * W_hh1[orow * H + kk];
                        else if (kk == 51) w = gsc * W_ih1[orow];   // x rides slot 51
                    }
                    wa1[s][j] = (_Float16)w;
                }
        }
        {
            const int arow = tw2 * 16 + n;
            const int cell = arow >> 2, gate = arow & 3;
            const int orow = gate * H + cell;
            const float gsc = (gate == 2) ? TWOLOG2E : LOG2E;
            const bool rok = (arow < 4 * H);
#pragma unroll
            for (int s = 0; s < 4; ++s)
#pragma unroll
                for (int j = 0; j < 8; ++j) {
                    int kk = s * 32 + qd * 8 + j;
                    float w = 0.f;
                    if (rok) {
                        if (kk < H)                       w = gsc * W_ih2[orow * H + kk];
                        else if (kk >= 64 && kk < 64 + H) w = gsc * W_hh2[orow * H + (kk - 64)];
                    } else if (arow == 204) {             // y row: W_lin
                        if (kk >= 64 && kk < 64 + H)      w = W_lin[kk - 64];
                    }
                    wa2[s][j] = (_Float16)w;
                }
        }
    }

    // ---- per-lane elementwise constants (same cell for both groups) ----
    const int ewv = (wv == 13 || wv == 14) ? 12 : ((wv < 12) ? wv : 13);
    const int jj  = ewv * 4 + qd;
    float4v bias1v, wih1v, bias2v;
    {
        const bool cok1 = (jj < H) && (wv < 12 || wv == 13);
        const bool cok2 = (jj < H) && (wv < 12 || wv == 14);
#pragma unroll
        for (int r = 0; r < 4; ++r) {
            const float gsc = (r == 2) ? TWOLOG2E : LOG2E;
            const int orow = r * H + jj;
            bias1v[r] = cok1 ? gsc * (b_ih1[orow] + b_hh1[orow]) : 0.f;
            wih1v[r]  = cok1 ? gsc * W_ih1[orow] : 0.f;   // prologue only
            bias2v[r] = cok2 ? gsc * (b_ih2[orow] + b_hh2[orow]) : 0.f;
        }
    }

    float c1A = 0.f, c2A = 0.f, c1B = 0.f, c2B = 0.f;
    const int js = jj >> 5, jq = (jj & 31) >> 3, j7 = jj & 7;

    __syncthreads();

    // ---- prologue: h1(0) both groups; seed x(1) both groups ----
    if (wv < 12 || wv == 13) {
        const float xbA = xss[0][0][n];
        const float xbB = xss[1][0][n];
        float4v aA, aB;
#pragma unroll
        for (int r = 0; r < 4; ++r) {
            aA[r] = fmaf(wih1v[r], xbA, bias1v[r]);
            aB[r] = fmaf(wih1v[r], xbB, bias1v[r]);
        }
        float hA = lstm_ew(aA, c1A);
        float hB = lstm_ew(aB, c1B);
        if (!(wv == 13 && qd == 3)) {
            ((_Float16*)&hb1[0][0][js][jq * 16 + n])[j7] = (_Float16)hA;
            ((_Float16*)&hb1[1][0][js][jq * 16 + n])[j7] = (_Float16)hB;
        }
    } else if (wv == 15) {
        if (lane < 32) {
            int g = lane >> 4, nn = lane & 15;
            ((_Float16*)&hb1[g][0][1][32 + nn])[3] = (_Float16)xss[g][0][17 + nn];
        }
    }
    __syncthreads();

    // ---- one step at compile-time parity P (both groups per barrier) ----
#define STEP(t, P)                                                              \
    {                                                                           \
        if (wv < 12) {                                                          \
            /* phase 1: g1 reads + mm1 + g1-half of mm2, groups interleaved */  \
            half8 g1A[2], g1B[2], g2A[2], g2B[2];                               \
            g1A[0] = hb1[0][P][0][lane];  g1A[1] = hb1[0][P][1][lane];          \
            g1B[0] = hb1[1][P][0][lane];  g1B[1] = hb1[1][P][1][lane];          \
            float4v a1A = bias1v;                                               \
            a1A = __builtin_amdgcn_mfma_f32_16x16x32_f16(wa1[0], g1A[0], a1A, 0, 0, 0); \
            a1A = __builtin_amdgcn_mfma_f32_16x16x32_f16(wa1[1], g1A[1], a1A, 0, 0, 0); \
            float4v a1B = bias1v;                                               \
            a1B = __builtin_amdgcn_mfma_f32_16x16x32_f16(wa1[0], g1B[0], a1B, 0, 0, 0); \
            a1B = __builtin_amdgcn_mfma_f32_16x16x32_f16(wa1[1], g1B[1], a1B, 0, 0, 0); \
            float4v a2A = bias2v;                                               \
            a2A = __builtin_amdgcn_mfma_f32_16x16x32_f16(wa2[0], g1A[0], a2A, 0, 0, 0); \
            a2A = __builtin_amdgcn_mfma_f32_16x16x32_f16(wa2[1], g1A[1], a2A, 0, 0, 0); \
            float4v a2B = bias2v;                                               \
            a2B = __builtin_amdgcn_mfma_f32_16x16x32_f16(wa2[0], g1B[0], a2B, 0, 0, 0); \
            a2B = __builtin_amdgcn_mfma_f32_16x16x32_f16(wa2[1], g1B[1], a2B, 0, 0, 0); \
            __builtin_amdgcn_sched_barrier(0);                                  \
            /* phase 2: g2 reads drain under the two independent ew1 chains */  \
            g2A[0] = hb2[0][P ^ 1][0][lane];  g2A[1] = hb2[0][P ^ 1][1][lane];  \
            g2B[0] = hb2[1][P ^ 1][0][lane];  g2B[1] = hb2[1][P ^ 1][1][lane];  \
            {                                                                   \
                float h = lstm_ew(a1A, c1A);                                    \
                ((_Float16*)&hb1[0][P ^ 1][js][jq * 16 + n])[j7] = (_Float16)h; \
            }                                                                   \
            {                                                                   \
                float h = lstm_ew(a1B, c1B);                                    \
                ((_Float16*)&hb1[1][P ^ 1][js][jq * 16 + n])[j7] = (_Float16)h; \
            }                                                                   \
            a2A = __builtin_amdgcn_mfma_f32_16x16x32_f16(wa2[2], g2A[0], a2A, 0, 0, 0); \
            a2A = __builtin_amdgcn_mfma_f32_16x16x32_f16(wa2[3], g2A[1], a2A, 0, 0, 0); \
            a2B = __builtin_amdgcn_mfma_f32_16x16x32_f16(wa2[2], g2B[0], a2B, 0, 0, 0); \
            a2B = __builtin_amdgcn_mfma_f32_16x16x32_f16(wa2[3], g2B[1], a2B, 0, 0, 0); \
            {                                                                   \
                float h = lstm_ew(a2A, c2A);                                    \
                ((_Float16*)&hb2[0][P][js][jq * 16 + n])[j7] = (_Float16)h;     \
            }                                                                   \
            {                                                                   \
                float h = lstm_ew(a2B, c2B);                                    \
                ((_Float16*)&hb2[1][P][js][jq * 16 + n])[j7] = (_Float16)h;     \
            }                                                                   \
        } else if (wv == 12) {                                                  \
            /* flush-only: both groups, slots disjoint from writer's slot */    \
            if ((t) > 64 && ((t) & 63) == 1) {                                  \
                const int tb = (t) - 65;                                        \
                const int sb = tb & 127;                                        \
                _Pragma("unroll")                                               \
                for (int r = 0; r < BB; ++r)                                    \
                    out[(size_t)(b0 + r) * TSEQ + tb + lane] =                  \
                        ybf[r >> 4][sb + lane][r & 15];                         \
            }                                                                   \
        } else if (wv == 13) {                                                  \
            /* tile-12 L1 both groups; qd=3 store suppressed (x-slot) */        \
            half8 g1A[2], g1B[2];                                               \
            g1A[0] = hb1[0][P][0][lane];  g1A[1] = hb1[0][P][1][lane];          \
            g1B[0] = hb1[1][P][0][lane];  g1B[1] = hb1[1][P][1][lane];          \
            float4v a1A = bias1v;                                               \
            a1A = __builtin_amdgcn_mfma_f32_16x16x32_f16(wa1[0], g1A[0], a1A, 0, 0, 0); \
            a1A = __builtin_amdgcn_mfma_f32_16x16x32_f16(wa1[1], g1A[1], a1A, 0, 0, 0); \
            float4v a1B = bias1v;                                               \
            a1B = __builtin_amdgcn_mfma_f32_16x16x32_f16(wa1[0], g1B[0], a1B, 0, 0, 0); \
            a1B = __builtin_amdgcn_mfma_f32_16x16x32_f16(wa1[1], g1B[1], a1B, 0, 0, 0); \
            float hA = lstm_ew(a1A, c1A);                                       \
            float hB = lstm_ew(a1B, c1B);                                       \
            if (qd != 3) {                                                      \
                ((_Float16*)&hb1[0][P ^ 1][js][jq * 16 + n])[j7] = (_Float16)hA; \
                ((_Float16*)&hb1[1][P ^ 1][js][jq * 16 + n])[j7] = (_Float16)hB; \
            }                                                                   \
        } else if (wv == 14) {                                                  \
            /* tile-12 L2 both groups: chained mm2 + ew2 + y (row 204) */       \
            half8 g1A[2], g1B[2], g2A[2], g2B[2];                               \
            g1A[0] = hb1[0][P][0][lane];  g1A[1] = hb1[0][P][1][lane];          \
            g1B[0] = hb1[1][P][0][lane];  g1B[1] = hb1[1][P][1][lane];          \
            float4v a2A = bias2v;                                               \
            a2A = __builtin_amdgcn_mfma_f32_16x16x32_f16(wa2[0], g1A[0], a2A, 0, 0, 0); \
            a2A = __builtin_amdgcn_mfma_f32_16x16x32_f16(wa2[1], g1A[1], a2A, 0, 0, 0); \
            float4v a2B = bias2v;                                               \
            a2B = __builtin_amdgcn_mfma_f32_16x16x32_f16(wa2[0], g1B[0], a2B, 0, 0, 0); \
            a2B = __builtin_amdgcn_mfma_f32_16x16x32_f16(wa2[1], g1B[1], a2B, 0, 0, 0); \
            __builtin_amdgcn_sched_barrier(0);                                  \
            g2A[0] = hb2[0][P ^ 1][0][lane];  g2A[1] = hb2[0][P ^ 1][1][lane];  \
            g2B[0] = hb2[1][P ^ 1][0][lane];  g2B[1] = hb2[1][P ^ 1][1][lane];  \
            a2A = __builtin_amdgcn_mfma_f32_16x16x32_f16(wa2[2], g2A[0], a2A, 0, 0, 0); \
            a2A = __builtin_amdgcn_mfma_f32_16x16x32_f16(wa2[3], g2A[1], a2A, 0, 0, 0); \
            a2B = __builtin_amdgcn_mfma_f32_16x16x32_f16(wa2[2], g2B[0], a2B, 0, 0, 0); \
            a2B = __builtin_amdgcn_mfma_f32_16x16x32_f16(wa2[3], g2B[1], a2B, 0, 0, 0); \
            float hA = lstm_ew(a2A, c2A);                                       \
            float hB = lstm_ew(a2B, c2B);                                       \
            ((_Float16*)&hb2[0][P][js][jq * 16 + n])[j7] = (_Float16)hA;        \
            ((_Float16*)&hb2[1][P][js][jq * 16 + n])[j7] = (_Float16)hB;        \
            if (qd == 3) {                                                      \
                ybf[0][((t) - 1) & 127][n] = a2A[0] + blin;                     \
                ybf[1][((t) - 1) & 127][n] = a2B[0] + blin;                     \
            }                                                                   \
        } else {                                                                \
            /* wave 15: x-forward both groups + prefetch 32 batches */          \
            const int t2 = (t) + 2;                                             \
            if (lane < 32) {                                                    \
                int g = lane >> 4, nn = lane & 15;                              \
                float xf = xss[g][(t2 >> 6) & 1][(t2 & 63) * 17 + nn];          \
                ((_Float16*)&hb1[g][P ^ 1][1][32 + nn])[3] = (_Float16)xf;      \
            }                                                                   \
            if (((t) & 63) == 32 && (t) + 32 < TSEQ) {                          \
                const int cp = ((t) >> 6) & 1;                                  \
                _Pragma("unroll")                                               \
                for (int k = 0; k < 32; ++k)                                    \
                    xss[k >> 4][cp ^ 1][lane * 17 + (k & 15)] =                 \
                        input[(size_t)(b0 + k) * TSEQ + ((t) + 32) + lane];     \
            }                                                                   \
        }                                                                       \
        __syncthreads();                                                        \
    }

#pragma unroll 1
    for (int t = 0; t < TSEQ; t += 2) {
        STEP(t, 0)
        STEP(t + 1, 1)
    }
#undef STEP

    // ---- epilogue: y(2047) both groups, then final flush ----
    if (wv == 14) {
#pragma unroll
        for (int g = 0; g < 2; ++g) {
            half8 g2a = hb2[g][1][0][lane], g2b = hb2[g][1][1][lane];
            float4v yb = (float4v){0.f, 0.f, 0.f, 0.f};
            yb = __builtin_amdgcn_mfma_f32_16x16x32_f16(wa2[2], g2a, yb, 0, 0, 0);
            yb = __builtin_amdgcn_mfma_f32_16x16x32_f16(wa2[3], g2b, yb, 0, 0, 0);
            if (qd == 3) ybf[g][127][n] = yb[0] + blin;   // y(2047)
        }
    }
    __syncthreads();
    if (wv == 12) {
        const int tb = TSEQ - 64;                  // 1984, sb = 64
#pragma unroll
        for (int r = 0; r < BB; ++r)
            out[(size_t)(b0 + r) * TSEQ + tb + lane] = ybf[r >> 4][64 + lane][r & 15];
    }
}

extern "C" void kernel_launch(void* const* d_in, const int* in_sizes, int n_in,
                              void* d_out, int out_size, void* d_ws, size_t ws_size,
                              hipStream_t stream) {
    const float* input = (const float*)d_in[0];
    const float* W_ih1 = (const float*)d_in[1];
    const float* W_hh1 = (const float*)d_in[2];
    const float* b_ih1 = (const float*)d_in[3];
    const float* b_hh1 = (const float*)d_in[4];
    const float* W_ih2 = (const float*)d_in[5];
    const float* W_hh2 = (const float*)d_in[6];
    const float* b_ih2 = (const float*)d_in[7];
    const float* b_hh2 = (const float*)d_in[8];
    const float* W_lin = (const float*)d_in[9];
    const float* b_lin = (const float*)d_in[10];

    lstm_w32_kernel<<<dim3(2048 / BB), dim3(THREADS), 0, stream>>>(
        input, W_ih1, W_hh1, b_ih1, b_hh1,
        W_ih2, W_hh2, b_ih2, b_hh2, W_lin, b_lin,
        (float*)d_out);
}

// Round 14
// 1173.267 us; speedup vs baseline: 1.6850x; 1.6850x over previous
//
#include <hip/hip_runtime.h>

#define H 51
#define TSEQ 2048
#define BB 16            // batch per block — fills all 16 MFMA columns
#define THREADS 1024     // 16 waves: 0-11 tiles, 12 flush, 13 L1-helper, 14 L2-helper+y, 15 pf+x

typedef _Float16 __attribute__((ext_vector_type(8))) half8;  // 8 f16 (MFMA A/B frag)
typedef float    __attribute__((ext_vector_type(4))) float4v;

#define LOG2E    1.44269504f
#define TWOLOG2E 2.88539008f

// Fused LSTM cell elementwise update: 7 transcendentals (5 exp2 + 2 rcp),
// fma-refactored.  Inputs pre-scaled: a[0]=i*log2e, a[1]=f*log2e,
// a[2]=g*2log2e, a[3]=o*log2e.
__device__ __forceinline__ float lstm_ew(float4v a, float& c) {
    float eA = __builtin_amdgcn_exp2f(-a[0]);
    float eB = __builtin_amdgcn_exp2f(a[2]);
    float eF = __builtin_amdgcn_exp2f(-a[1]);
    float pA = eA + 1.0f, pB = eB + 1.0f, pF = eF + 1.0f;
    float dAB = pA * pB;
    float t0  = fmaf(eB, pF, -pF);                 // (eB-1)*pF
    float num = fmaf(c, dAB, t0);
    float r   = __builtin_amdgcn_rcpf(dAB * pF);
    float cn  = num * r;
    c = cn;
    float uD = fminf(cn * TWOLOG2E, 126.0f);
    float eD = __builtin_amdgcn_exp2f(uD);
    float eC = __builtin_amdgcn_exp2f(-a[3]);
    float pD = eD + 1.0f;
    float r2 = __builtin_amdgcn_rcpf(fmaf(eC, pD, pD));  // (eC+1)*pD
    return fmaf(eD, r2, -r2);                      // (eD-1)*r2
}

// R14 = R12 exactly (1208us; R13's BB=32 reverted — wall time = T x step-time,
// and 2x work/step filled bubbles at only 36% efficiency -> +64%) + phase-1
// targeted s_setprio on the h1-producing waves ONLY:
//  post-barrier, 16 waves resume at once; any issue-contention delay on the
//  g1-read/mm1 start lengthens the EXPOSED h1 chain (proven by R10 overshoot
//  / R11 delay-regression) and thus the barrier interval.  wv<12 and wv13 run
//  at prio 1 from barrier until their hb1 write, then drop to 0 so wave 14
//  (hb2 producer) owns the back half.  R5's setprio null wrapped ALL waves —
//  this is the role-diverse variant (T5 prerequisite).  Math bit-identical.
//  Carried: x-injection slot 51 (R8), split-phase reads (R7), y-fold row 204
//  (R5), recompute helpers (R4), chained mm2 (R12), fma ew (R10).
__global__ __launch_bounds__(THREADS)
void lstm_w16i_kernel(const float* __restrict__ input,
                      const float* __restrict__ W_ih1, const float* __restrict__ W_hh1,
                      const float* __restrict__ b_ih1, const float* __restrict__ b_hh1,
                      const float* __restrict__ W_ih2, const float* __restrict__ W_hh2,
                      const float* __restrict__ b_ih2, const float* __restrict__ b_hh2,
                      const float* __restrict__ W_lin, const float* __restrict__ b_lin,
                      float* __restrict__ out)
{
    __shared__ half8 hb1[2][2][64];      // [parity][kstep][fraglane]
    __shared__ half8 hb2[2][2][64];
    __shared__ float xss[2][64 * 17];    // x chunks [i*17+b]
    __shared__ float ybf[128][17];       // y slots [t&127][batch], conflict-free

    const int tid  = threadIdx.x;
    const int wv   = tid >> 6;           // 0..15
    const int lane = tid & 63;
    const int n    = lane & 15;          // MFMA col = batch
    const int qd   = lane >> 4;          // quad
    const int b0   = blockIdx.x * BB;
    const float blin = b_lin[0];

    if (tid < 256) {
        half8 z = {0,0,0,0,0,0,0,0};
        (&hb1[0][0][0])[tid] = z;
        (&hb2[0][0][0])[tid] = z;
    }

    if (wv == 15) {                      // x chunk 0 (all 16 batches)
#pragma unroll
        for (int k = 0; k < 16; ++k)
            xss[0][lane * 17 + k] = input[(size_t)(b0 + k) * TSEQ + lane];
    }

    // ---- persistent A-fragments, plain f16, gate rows pre-scaled ----
    // wa1: waves 0-11 tiles 0-11; wave 13 tile 12; rest zeros.
    //      slot kk=51 carries gsc*W_ih1[row] (x-injection).
    // wa2: waves 0-11 tiles 0-11; wave 14 tile 12; rest zeros.
    //      arow 204 (wave 14, lane n=12) W_hh2-slot carries W_lin (scale 1).
    half8 wa1[2];                        // W_hh1 (K=64) + W_ih1 at k=51
    half8 wa2[4];                        // s<2: W_ih2 (k=h1); s>=2: W_hh2 (k=h2)
    {
        const int tw1 = (wv < 12) ? wv : ((wv == 13) ? 12 : 13);  // 13 -> rows>=208 -> zero
        const int tw2 = (wv < 12) ? wv : ((wv == 14) ? 12 : 13);
        {
            const int arow = tw1 * 16 + n;
            const int cell = arow >> 2, gate = arow & 3;
            const int orow = gate * H + cell;
            const float gsc = (gate == 2) ? TWOLOG2E : LOG2E;
            const bool rok = (arow < 4 * H);
#pragma unroll
            for (int s = 0; s < 2; ++s)
#pragma unroll
                for (int j = 0; j < 8; ++j) {
                    int kk = s * 32 + qd * 8 + j;
                    float w = 0.f;
                    if (rok) {
                        if (kk < H)        w = gsc * W_hh1[orow * H + kk];
                        else if (kk == 51) w = gsc * W_ih1[orow];   // x rides B-slot 51
                    }
                    wa1[s][j] = (_Float16)w;
                }
        }
        {
            const int arow = tw2 * 16 + n;
            const int cell = arow >> 2, gate = arow & 3;
            const int orow = gate * H + cell;
            const float gsc = (gate == 2) ? TWOLOG2E : LOG2E;
            const bool rok = (arow < 4 * H);
#pragma unroll
            for (int s = 0; s < 4; ++s)
#pragma unroll
                for (int j = 0; j < 8; ++j) {
                    int kk = s * 32 + qd * 8 + j;
                    float w = 0.f;
                    if (rok) {
                        if (kk < H)                       w = gsc * W_ih2[orow * H + kk];
                        else if (kk >= 64 && kk < 64 + H) w = gsc * W_hh2[orow * H + (kk - 64)];
                    } else if (arow == 204) {             // y row: W_lin, no gate scale
                        if (kk >= 64 && kk < 64 + H)      w = W_lin[kk - 64];
                    }
                    wa2[s][j] = (_Float16)w;
                }
        }
    }

    // ---- per-lane elementwise constants ----
    const int ewv = (wv == 13 || wv == 14) ? 12 : ((wv < 12) ? wv : 13);
    const int jj  = ewv * 4 + qd;        // wv 12/15 -> jj>=52 -> all cok false
    float4v bias1v, wih1v, bias2v;
    {
        const bool cok1 = (jj < H) && (wv < 12 || wv == 13);  // L1 ew owners
        const bool cok2 = (jj < H) && (wv < 12 || wv == 14);  // L2 ew owners
#pragma unroll
        for (int r = 0; r < 4; ++r) {
            const float gsc = (r == 2) ? TWOLOG2E : LOG2E;
            const int orow = r * H + jj;
            bias1v[r] = cok1 ? gsc * (b_ih1[orow] + b_hh1[orow]) : 0.f;
            wih1v[r]  = cok1 ? gsc * W_ih1[orow] : 0.f;   // prologue only
            bias2v[r] = cok2 ? gsc * (b_ih2[orow] + b_hh2[orow]) : 0.f;
        }
    }

    float c1 = 0.f, c2 = 0.f;
    const int js = jj >> 5, jq = (jj & 31) >> 3, j7 = jj & 7;   // h store coords

    __syncthreads();

    // ---- prologue: h1(0) = ew(bias1 + Wih1*x(0)); seed x(1) into hb1[0] ----
    if (wv < 12 || wv == 13) {
        const float xb = xss[0][n];
        float4v a;
#pragma unroll
        for (int r = 0; r < 4; ++r) a[r] = fmaf(wih1v[r], xb, bias1v[r]);
        float h = lstm_ew(a, c1);
        if (!(wv == 13 && qd == 3))
            ((_Float16*)&hb1[0][js][jq * 16 + n])[j7] = (_Float16)h;
    } else if (wv == 15) {
        if (lane < 16)
            ((_Float16*)&hb1[0][1][32 + lane])[3] = (_Float16)xss[0][17 + lane];
    }
    __syncthreads();

    // ---- one step at compile-time parity P ----
#define STEP(t, P)                                                              \
    {                                                                           \
        if (wv < 12) {                                                          \
            /* phase 1 (prio 1): g1 reads, mm1 + g1-half of mm2 chain */        \
            __builtin_amdgcn_s_setprio(1);                                      \
            half8 g1[2], g2[2];                                                 \
            g1[0] = hb1[P][0][lane];      g1[1] = hb1[P][1][lane];              \
            float4v a1 = bias1v;                                                \
            a1 = __builtin_amdgcn_mfma_f32_16x16x32_f16(wa1[0], g1[0], a1, 0, 0, 0); \
            a1 = __builtin_amdgcn_mfma_f32_16x16x32_f16(wa1[1], g1[1], a1, 0, 0, 0); \
            float4v a2 = bias2v;                                                \
            a2 = __builtin_amdgcn_mfma_f32_16x16x32_f16(wa2[0], g1[0], a2, 0, 0, 0); \
            a2 = __builtin_amdgcn_mfma_f32_16x16x32_f16(wa2[1], g1[1], a2, 0, 0, 0); \
            __builtin_amdgcn_sched_barrier(0);                                  \
            /* phase 2: g2 reads issued here; latency drains under ew1 */       \
            g2[0] = hb2[P ^ 1][0][lane];  g2[1] = hb2[P ^ 1][1][lane];          \
            {                                                                   \
                float h = lstm_ew(a1, c1);                                      \
                ((_Float16*)&hb1[P ^ 1][js][jq * 16 + n])[j7] = (_Float16)h;    \
            }                                                                   \
            __builtin_amdgcn_s_setprio(0);                                      \
            a2 = __builtin_amdgcn_mfma_f32_16x16x32_f16(wa2[2], g2[0], a2, 0, 0, 0); \
            a2 = __builtin_amdgcn_mfma_f32_16x16x32_f16(wa2[3], g2[1], a2, 0, 0, 0); \
            {                                                                   \
                float h = lstm_ew(a2, c2);                                      \
                ((_Float16*)&hb2[P][js][jq * 16 + n])[j7] = (_Float16)h;        \
            }                                                                   \
        } else if (wv == 12) {                                                  \
            /* flush-only: chunk closed; slots disjoint from writer's slot */   \
            if ((t) > 64 && ((t) & 63) == 1) {                                  \
                const int tb = (t) - 65;                                        \
                const int sb = tb & 127;                                        \
                _Pragma("unroll")                                               \
                for (int r = 0; r < BB; ++r)                                    \
                    out[(size_t)(b0 + r) * TSEQ + tb + lane] = ybf[sb + lane][r]; \
            }                                                                   \
        } else if (wv == 13) {                                                  \
            /* tile-12 L1 (prio 1): mm1 + ew1; qd=3 store suppressed (x-slot) */ \
            __builtin_amdgcn_s_setprio(1);                                      \
            half8 g1[2];                                                        \
            g1[0] = hb1[P][0][lane];      g1[1] = hb1[P][1][lane];              \
            float4v a1 = bias1v;                                                \
            a1 = __builtin_amdgcn_mfma_f32_16x16x32_f16(wa1[0], g1[0], a1, 0, 0, 0); \
            a1 = __builtin_amdgcn_mfma_f32_16x16x32_f16(wa1[1], g1[1], a1, 0, 0, 0); \
            float h = lstm_ew(a1, c1);                                          \
            if (qd != 3)                                                        \
                ((_Float16*)&hb1[P ^ 1][js][jq * 16 + n])[j7] = (_Float16)h;    \
            __builtin_amdgcn_s_setprio(0);                                      \
        } else if (wv == 14) {                                                  \
            /* tile-12 L2: chained mm2 + ew2 + y-extract (row 204 = W_lin) */   \
            half8 g1[2], g2[2];                                                 \
            g1[0] = hb1[P][0][lane];      g1[1] = hb1[P][1][lane];              \
            float4v a2 = bias2v;                                                \
            a2 = __builtin_amdgcn_mfma_f32_16x16x32_f16(wa2[0], g1[0], a2, 0, 0, 0); \
            a2 = __builtin_amdgcn_mfma_f32_16x16x32_f16(wa2[1], g1[1], a2, 0, 0, 0); \
            __builtin_amdgcn_sched_barrier(0);                                  \
            g2[0] = hb2[P ^ 1][0][lane];  g2[1] = hb2[P ^ 1][1][lane];          \
            a2 = __builtin_amdgcn_mfma_f32_16x16x32_f16(wa2[2], g2[0], a2, 0, 0, 0); \
            a2 = __builtin_amdgcn_mfma_f32_16x16x32_f16(wa2[3], g2[1], a2, 0, 0, 0); \
            float h = lstm_ew(a2, c2);                                          \
            ((_Float16*)&hb2[P][js][jq * 16 + n])[j7] = (_Float16)h;            \
            if (qd == 3) ybf[((t) - 1) & 127][n] = a2[0] + blin;  /* y(t-1) */  \
        } else {                                                                \
            /* wave 15: x-forward (x(t+2) -> hb1[P^1] slot 51) + prefetch */    \
            const int t2 = (t) + 2;                                             \
            if (lane < 16) {                                                    \
                float xf = xss[(t2 >> 6) & 1][(t2 & 63) * 17 + lane];           \
                ((_Float16*)&hb1[P ^ 1][1][32 + lane])[3] = (_Float16)xf;       \
            }                                                                   \
            if (((t) & 63) == 32 && (t) + 32 < TSEQ) {                          \
                const int cp = ((t) >> 6) & 1;                                  \
                _Pragma("unroll")                                               \
                for (int k = 0; k < 16; ++k)                                    \
                    xss[cp ^ 1][lane * 17 + k] =                                \
                        input[(size_t)(b0 + k) * TSEQ + ((t) + 32) + lane];     \
            }                                                                   \
        }                                                                       \
        __syncthreads();                                                        \
    }

#pragma unroll 1
    for (int t = 0; t < TSEQ; t += 2) {
        STEP(t, 0)
        STEP(t + 1, 1)
    }
#undef STEP

    // ---- epilogue: y(2047) via one extra mm2-half on h2(2047), then flush ----
    if (wv == 14) {
        half8 g2a = hb2[1][0][lane], g2b = hb2[1][1][lane];
        float4v yb = (float4v){0.f, 0.f, 0.f, 0.f};
        yb = __builtin_amdgcn_mfma_f32_16x16x32_f16(wa2[2], g2a, yb, 0, 0, 0);
        yb = __builtin_amdgcn_mfma_f32_16x16x32_f16(wa2[3], g2b, yb, 0, 0, 0);
        if (qd == 3) ybf[127][n] = yb[0] + blin;   // y(2047), slot 2047&127
    }
    __syncthreads();
    if (wv == 12) {
        const int tb = TSEQ - 64;                  // 1984, sb = 64
#pragma unroll
        for (int r = 0; r < BB; ++r)
            out[(size_t)(b0 + r) * TSEQ + tb + lane] = ybf[64 + lane][r];
    }
}

extern "C" void kernel_launch(void* const* d_in, const int* in_sizes, int n_in,
                              void* d_out, int out_size, void* d_ws, size_t ws_size,
                              hipStream_t stream) {
    const float* input = (const float*)d_in[0];
    const float* W_ih1 = (const float*)d_in[1];
    const float* W_hh1 = (const float*)d_in[2];
    const float* b_ih1 = (const float*)d_in[3];
    const float* b_hh1 = (const float*)d_in[4];
    const float* W_ih2 = (const float*)d_in[5];
    const float* W_hh2 = (const float*)d_in[6];
    const float* b_ih2 = (const float*)d_in[7];
    const float* b_hh2 = (const float*)d_in[8];
    const float* W_lin = (const float*)d_in[9];
    const float* b_lin = (const float*)d_in[10];

    lstm_w16i_kernel<<<dim3(2048 / BB), dim3(THREADS), 0, stream>>>(
        input, W_ih1, W_hh1, b_ih1, b_hh1,
        W_ih2, W_hh2, b_ih2, b_hh2, W_lin, b_lin,
        (float*)d_out);
}